// Round 3
// baseline (580.388 us; speedup 1.0000x reference)
//
#include <hip/hip_runtime.h>

#define BB 16
#define DD 512
#define TT 4096
#define KK 1024

typedef _Float16 h16;
typedef __attribute__((ext_vector_type(8))) _Float16 half8;
typedef __attribute__((ext_vector_type(4))) float float4v;

// ---- ws layout (main path), bytes ----
// xth/xtl tiled: [b][tb(32)][dcb(16)][128][32] halfs -> 64 MiB per plane
// cbh/cbl tiled: [kb(8)][dcb(16)][128][32] halfs    -> 1 MiB per plane
//   NOTE: cb planes are linear in g = kci*16+dcb  (offset g*4096 halfs).
#define XTH_OFF 0ull
#define XTL_OFF 67108864ull
#define CBH_OFF 134217728ull
#define CBL_OFF 135266304ull
#define CSQ_OFF 136314880ull
#define WS_NEED (136314880ull + 4096ull)

#define GLOAD_LDS16(g, l) __builtin_amdgcn_global_load_lds( \
    (const __attribute__((address_space(1))) void*)(g),      \
    (__attribute__((address_space(3))) void*)(l), 16, 0, 0)

// ---------------------------------------------------------------------------
// csq[k] = sum_d cb[k][d]^2
// ---------------------------------------------------------------------------
__global__ void csq_kernel(const float* __restrict__ cb, float* __restrict__ csq) {
    int wave = threadIdx.x >> 6;
    int lane = threadIdx.x & 63;
    int row  = blockIdx.x * 4 + wave;
    const float* r = cb + (size_t)row * DD;
    float s = 0.f;
    #pragma unroll
    for (int i = 0; i < DD / 64; ++i) { float v = r[lane + i * 64]; s += v * v; }
    #pragma unroll
    for (int off = 32; off; off >>= 1) s += __shfl_down(s, off, 64);
    if (lane == 0) csq[row] = s;
}

// ---------------------------------------------------------------------------
// split x [B][D][T] fp32 -> tiled f16 planes [b][tb][dcb][128][32].
// ---------------------------------------------------------------------------
__global__ __launch_bounds__(256) void split_x_kernel(const float* __restrict__ x,
                                                      h16* __restrict__ xth,
                                                      h16* __restrict__ xtl) {
    __shared__ float xs[32][132];  // float4-stored rows, 16B-aligned stride
    const int tb = blockIdx.x, dcb = blockIdx.y, b = blockIdx.z;
    const int tid = threadIdx.x;
    const int t0 = tb * 128, d0 = dcb * 32;
    const float* xp = x + ((size_t)b * DD + d0) * TT + t0;
    #pragma unroll
    for (int j = 0; j < 4; ++j) {
        int i4 = tid + 256 * j;
        int dd = i4 >> 5, c4 = (i4 & 31) << 2;
        *(float4*)&xs[dd][c4] = *(const float4*)(xp + (size_t)dd * TT + c4);
    }
    __syncthreads();
    const int r = tid >> 1;              // t-local row of output
    const int ch = (tid & 1) * 16;       // d-half
    h16 hv[16], lv[16];
    #pragma unroll
    for (int i = 0; i < 16; ++i) {
        float v = xs[ch + i][r];
        h16 h = (h16)v;
        hv[i] = h;
        lv[i] = (h16)(v - (float)h);
    }
    size_t o = (((size_t)(b * 32 + tb) * 16) + dcb) * 4096 + (size_t)tid * 16;
    *(half8*)(xth + o)     = *(half8*)&hv[0];
    *(half8*)(xth + o + 8) = *(half8*)&hv[8];
    *(half8*)(xtl + o)     = *(half8*)&lv[0];
    *(half8*)(xtl + o + 8) = *(half8*)&lv[8];
}

// ---------------------------------------------------------------------------
// split cb [K][D] fp32 -> tiled f16 planes [kb][dcb][128][32]. No transpose.
// ---------------------------------------------------------------------------
__global__ __launch_bounds__(256) void split_cb_kernel(const float* __restrict__ cb,
                                                       h16* __restrict__ cbh,
                                                       h16* __restrict__ cbl) {
    const int kb = blockIdx.x >> 4, dcb = blockIdx.x & 15;
    const int tid = threadIdx.x;
    const float* cp = cb + ((size_t)kb * 128) * DD + dcb * 32;
    h16* oh = cbh + ((size_t)(kb * 16 + dcb)) * 4096;
    h16* ol = cbl + ((size_t)(kb * 16 + dcb)) * 4096;
    #pragma unroll
    for (int j = 0; j < 4; ++j) {
        int i4 = tid + 256 * j;
        int rr = i4 >> 3, c4 = (i4 & 7) << 2;
        float4 v = *(const float4*)(cp + (size_t)rr * DD + c4);
        float vv[4] = {v.x, v.y, v.z, v.w};
        h16 h[4], l[4];
        #pragma unroll
        for (int i = 0; i < 4; ++i) {
            h[i] = (h16)vv[i];
            l[i] = (h16)(vv[i] - (float)h[i]);
        }
        *(ushort4*)(oh + rr * 32 + c4) = *(ushort4*)h;
        *(ushort4*)(ol + rr * 32 + c4) = *(ushort4*)l;
    }
}

// ---------------------------------------------------------------------------
// fused f16x3-split MFMA GEMM + argmin + gather.
// score[t][k] = csq[k] - 2 * (xh.bh + xh.bl + xl.bh)
// v4: phase-interleaved schedule. Frag reads pipelined ONE iter ahead with
// static even/odd register sets; 24-MFMA cluster split 12+12 so that
//   - stage-issue + B-read retire hide under h1,
//   - vmcnt(4) (counted, never 0 mid-loop) sits after h1,
//   - next-iter A-frag ds_reads hide under h2.
// Per-acc MFMA order AhBh -> AhBl -> AlBh unchanged -> bit-identical.
// ---------------------------------------------------------------------------
__global__ __launch_bounds__(512, 4) void mfma_argmin_kernel(
    const h16* __restrict__ xth, const h16* __restrict__ xtl,
    const h16* __restrict__ cbh, const h16* __restrict__ cbl,
    const float* __restrict__ csq, const float* __restrict__ cb,
    float* __restrict__ idx_f_out, float* __restrict__ out) {

    __shared__ h16 ash[2][4096];
    __shared__ h16 asl[2][4096];
    __shared__ h16 bsh[2][4096];
    __shared__ h16 bsl[2][4096];
    __shared__ float redv[4][128];
    __shared__ int   redi[4][128];

    const int tid = threadIdx.x;
    const int wid = tid >> 6, lane = tid & 63;
    const int wm = wid & 1;            // t-half of tile (0/1)
    const int wn = wid >> 1;           // k-quarter of tile (0..3)
    const int tb = blockIdx.x, b = blockIdx.y;
    const int t0 = tb * 128;
    const int c  = lane & 15;          // frag col
    const int q  = lane >> 4;          // frag quad

    const h16* aH = xth + ((size_t)(b * 32 + tb) * 16) * 4096;
    const h16* aL = xtl + ((size_t)(b * 32 + tb) * 16) * 4096;

    const int soff = tid * 8;          // halfs: 512 lanes x 16B = one 8 KiB plane
    const int doff = q * 8;

    int arow[4], brow[2];
    #pragma unroll
    for (int m = 0; m < 4; ++m) arow[m] = (wm * 64 + m * 16 + c) * 32 + doff;
    #pragma unroll
    for (int n = 0; n < 2; ++n) brow[n] = (wn * 32 + n * 16 + c) * 32 + doff;

    // prologue: stage tile g=0 -> buf0, g=1 -> buf1
    GLOAD_LDS16(aH  + soff,        &ash[0][soff]);
    GLOAD_LDS16(aL  + soff,        &asl[0][soff]);
    GLOAD_LDS16(cbh + soff,        &bsh[0][soff]);
    GLOAD_LDS16(cbl + soff,        &bsl[0][soff]);
    GLOAD_LDS16(aH  + 4096 + soff, &ash[1][soff]);
    GLOAD_LDS16(aL  + 4096 + soff, &asl[1][soff]);
    GLOAD_LDS16(cbh + 4096 + soff, &bsh[1][soff]);
    GLOAD_LDS16(cbl + 4096 + soff, &bsl[1][soff]);

    float best[16];
    int   bidx[16];
    #pragma unroll
    for (int i = 0; i < 16; ++i) { best[i] = 3.4e38f; bidx[i] = 0; }

    float4v acc[4][2];
    #pragma unroll
    for (int m = 0; m < 4; ++m)
        #pragma unroll
        for (int n = 0; n < 2; ++n)
            acc[m][n] = (float4v){0.f, 0.f, 0.f, 0.f};

    asm volatile("s_waitcnt vmcnt(4)" ::: "memory");   // t(0) resident
    __builtin_amdgcn_s_barrier();

    // pre-read A-frags of tile 0 (set 0)
    half8 Ah0[4], Al0[4], Ah1[4], Al1[4];
    #pragma unroll
    for (int m = 0; m < 4; ++m) {
        Ah0[m] = *(const half8*)(&ash[0][arow[m]]);
        Al0[m] = *(const half8*)(&asl[0][arow[m]]);
    }

#define MFMA16(a, bv, d) d = __builtin_amdgcn_mfma_f32_16x16x32_f16(a, bv, d, 0, 0, 0)

#define BODY(G, BF, AhC, AlC, AhN, AlN) do {                                     \
    /* JIT B-frag reads of tile G from buf[BF] */                                \
    half8 Bh0 = *(const half8*)(&bsh[BF][brow[0]]);                              \
    half8 Bl0 = *(const half8*)(&bsl[BF][brow[0]]);                              \
    half8 Bh1 = *(const half8*)(&bsh[BF][brow[1]]);                              \
    half8 Bl1 = *(const half8*)(&bsl[BF][brow[1]]);                              \
    asm volatile("s_waitcnt lgkmcnt(0)" ::: "memory");                           \
    __builtin_amdgcn_s_barrier();   /* all waves' reads of buf[BF] retired */    \
    __builtin_amdgcn_sched_barrier(0);                                           \
    if ((G) + 2 < 128) {            /* stage tile G+2 into freed buf[BF] */      \
        const int dn_ = ((G) + 2) & 15;                                          \
        GLOAD_LDS16(aH + (size_t)dn_ * 4096 + soff,        &ash[BF][soff]);      \
        GLOAD_LDS16(aL + (size_t)dn_ * 4096 + soff,        &asl[BF][soff]);      \
        GLOAD_LDS16(cbh + (size_t)((G) + 2) * 4096 + soff, &bsh[BF][soff]);      \
        GLOAD_LDS16(cbl + (size_t)((G) + 2) * 4096 + soff, &bsl[BF][soff]);      \
    }                                                                            \
    __builtin_amdgcn_s_setprio(1);  /* h1: AhBh(8) + AhBl n=0 (4) */             \
    MFMA16(AhC[0], Bh0, acc[0][0]); MFMA16(AhC[1], Bh0, acc[1][0]);              \
    MFMA16(AhC[2], Bh0, acc[2][0]); MFMA16(AhC[3], Bh0, acc[3][0]);              \
    MFMA16(AhC[0], Bh1, acc[0][1]); MFMA16(AhC[1], Bh1, acc[1][1]);              \
    MFMA16(AhC[2], Bh1, acc[2][1]); MFMA16(AhC[3], Bh1, acc[3][1]);              \
    MFMA16(AhC[0], Bl0, acc[0][0]); MFMA16(AhC[1], Bl0, acc[1][0]);              \
    MFMA16(AhC[2], Bl0, acc[2][0]); MFMA16(AhC[3], Bl0, acc[3][0]);              \
    __builtin_amdgcn_s_setprio(0);                                               \
    if ((G) + 2 < 128)      asm volatile("s_waitcnt vmcnt(4)" ::: "memory");     \
    else if ((G) + 1 < 128) asm volatile("s_waitcnt vmcnt(0)" ::: "memory");     \
    __builtin_amdgcn_s_barrier();   /* tile G+1 published in buf[BF^1] */        \
    __builtin_amdgcn_sched_barrier(0);                                           \
    if ((G) + 1 < 128) {            /* read-ahead A-frags of tile G+1 */         \
        _Pragma("unroll")                                                        \
        for (int m = 0; m < 4; ++m) {                                            \
            AhN[m] = *(const half8*)(&ash[(BF) ^ 1][arow[m]]);                   \
            AlN[m] = *(const half8*)(&asl[(BF) ^ 1][arow[m]]);                   \
        }                                                                        \
    }                                                                            \
    __builtin_amdgcn_s_setprio(1);  /* h2: AhBl n=1 (4) + AlBh(8) */             \
    MFMA16(AhC[0], Bl1, acc[0][1]); MFMA16(AhC[1], Bl1, acc[1][1]);              \
    MFMA16(AhC[2], Bl1, acc[2][1]); MFMA16(AhC[3], Bl1, acc[3][1]);              \
    MFMA16(AlC[0], Bh0, acc[0][0]); MFMA16(AlC[1], Bh0, acc[1][0]);              \
    MFMA16(AlC[2], Bh0, acc[2][0]); MFMA16(AlC[3], Bh0, acc[3][0]);              \
    MFMA16(AlC[0], Bh1, acc[0][1]); MFMA16(AlC[1], Bh1, acc[1][1]);              \
    MFMA16(AlC[2], Bh1, acc[2][1]); MFMA16(AlC[3], Bh1, acc[3][1]);              \
    __builtin_amdgcn_s_setprio(0);                                               \
} while (0)

    for (int gp = 0; gp < 64; ++gp) {
        const int g0 = gp * 2;
        BODY(g0,     0, Ah0, Al0, Ah1, Al1);
        BODY(g0 + 1, 1, Ah1, Al1, Ah0, Al0);

        if ((gp & 7) == 7) {
            // fold k-chunk into running argmin (k ascending => first-index tie-break)
            const int kci = gp >> 3;
            #pragma unroll
            for (int n = 0; n < 2; ++n) {
                int kg = kci * 128 + wn * 32 + n * 16 + c;
                float cq = csq[kg];
                #pragma unroll
                for (int m = 0; m < 4; ++m)
                    #pragma unroll
                    for (int r = 0; r < 4; ++r) {
                        float s = fmaf(-2.0f, acc[m][n][r], cq);
                        int slot = m * 4 + r;
                        if (s < best[slot]) { best[slot] = s; bidx[slot] = kg; }
                    }
            }
            #pragma unroll
            for (int m = 0; m < 4; ++m)
                #pragma unroll
                for (int n = 0; n < 2; ++n)
                    acc[m][n] = (float4v){0.f, 0.f, 0.f, 0.f};
        }
    }
#undef BODY
#undef MFMA16

    // reduce over the 16 frag columns (lanes sharing a t)
    #pragma unroll
    for (int slot = 0; slot < 16; ++slot) {
        float v = best[slot]; int i = bidx[slot];
        #pragma unroll
        for (int d = 1; d < 16; d <<= 1) {
            float pv = __shfl_xor(v, d);
            int   pi = __shfl_xor(i, d);
            if (pv < v || (pv == v && pi < i)) { v = pv; i = pi; }
        }
        if (c == 0) {
            int m = slot >> 2, r = slot & 3;
            int tl = wm * 64 + m * 16 + q * 4 + r;
            redv[wn][tl] = v; redi[wn][tl] = i;
        }
    }
    __syncthreads();
    if (tid < 128) {
        float v0 = redv[0][tid]; int i0 = redi[0][tid];
        #pragma unroll
        for (int gi = 1; gi < 4; ++gi) {
            float v1 = redv[gi][tid]; int i1 = redi[gi][tid];
            if (v1 < v0 || (v1 == v0 && i1 < i0)) { v0 = v1; i0 = i1; }
        }
        idx_f_out[(size_t)b * TT + t0 + tid] = (float)i0;
        redi[0][tid] = i0;                 // broadcast final index
    }
    __syncthreads();

    // fused gather: out[b][d][t0+tl] = cb[k][d]; 512 threads -> 128 d each
    const int tl = tid & 127, dg = tid >> 7;
    const int k = redi[0][tl];
    const float* row = cb + (size_t)k * DD + dg * 128;
    float* ob = out + ((size_t)b * DD + dg * 128) * TT + t0 + tl;
    #pragma unroll 4
    for (int i = 0; i < 32; ++i) {
        float4 v = *(const float4*)(row + i * 4);
        ob[(size_t)(i * 4 + 0) * TT] = v.x;
        ob[(size_t)(i * 4 + 1) * TT] = v.y;
        ob[(size_t)(i * 4 + 2) * TT] = v.z;
        ob[(size_t)(i * 4 + 3) * TT] = v.w;
    }
}

// ---------------------------------------------------------------------------
// fallback fp32 path + standalone gather (used only if ws too small)
// ---------------------------------------------------------------------------
__global__ void gather_kernel(const float* __restrict__ cb,
                              const float* __restrict__ idx_f,
                              float* __restrict__ out) {
    int b  = blockIdx.y;
    int t  = blockIdx.x * 256 + threadIdx.x;
    int d0 = blockIdx.z * (DD / 4);
    int k  = (int)idx_f[(size_t)b * TT + t];
    const float* row = cb + (size_t)k * DD;
    float* ob = out + (size_t)b * DD * TT + t;
    #pragma unroll 8
    for (int d = d0; d < d0 + DD / 4; ++d)
        ob[(size_t)d * TT] = row[d];
}

__global__ __launch_bounds__(256) void argmin_fp32_kernel(
    const float* __restrict__ x, const float* __restrict__ cb,
    const float* __restrict__ csq, float* __restrict__ idx_f_out) {

    __shared__ float xs[32][128];
    __shared__ float cs[32][132];

    const int tid = threadIdx.x;
    const int b = blockIdx.y;
    const int t_blk = blockIdx.x * 128;
    const int tq = tid & 15, kq = tid >> 4;
    const int t0 = tq * 8, k0 = kq * 8;
    const float* xb = x + (size_t)b * DD * TT;

    float best[8]; int bidx[8];
    #pragma unroll
    for (int i = 0; i < 8; ++i) { best[i] = 3.4e38f; bidx[i] = 0; }

    for (int kc = 0; kc < KK; kc += 128) {
        float acc[8][8];
        #pragma unroll
        for (int i = 0; i < 8; ++i)
            #pragma unroll
            for (int j = 0; j < 8; ++j) acc[i][j] = 0.f;
        for (int dc = 0; dc < DD; dc += 32) {
            __syncthreads();
            #pragma unroll
            for (int j = 0; j < 4; ++j) {
                int i4 = tid + 256 * j;
                int dd = i4 >> 5, tp = (i4 & 31) << 2;
                *(float4*)&xs[dd][tp] =
                    *(const float4*)(xb + (size_t)(dc + dd) * TT + t_blk + tp);
            }
            #pragma unroll
            for (int j = 0; j < 4; ++j) {
                int i4 = tid + 256 * j;
                int kk = i4 >> 3, dq = (i4 & 7) << 2;
                float4 v = *(const float4*)(cb + (size_t)(kc + kk) * DD + dc + dq);
                cs[dq + 0][kk] = v.x; cs[dq + 1][kk] = v.y;
                cs[dq + 2][kk] = v.z; cs[dq + 3][kk] = v.w;
            }
            __syncthreads();
            #pragma unroll 8
            for (int dd = 0; dd < 32; ++dd) {
                float a[8], bv[8];
                *(float4*)&a[0]  = *(const float4*)&xs[dd][t0];
                *(float4*)&a[4]  = *(const float4*)&xs[dd][t0 + 4];
                *(float4*)&bv[0] = *(const float4*)&cs[dd][k0];
                *(float4*)&bv[4] = *(const float4*)&cs[dd][k0 + 4];
                #pragma unroll
                for (int i = 0; i < 8; ++i)
                    #pragma unroll
                    for (int j = 0; j < 8; ++j)
                        acc[i][j] = fmaf(a[i], bv[j], acc[i][j]);
            }
        }
        #pragma unroll
        for (int j = 0; j < 8; ++j) {
            int kg = kc + k0 + j;
            float cq = csq[kg];
            #pragma unroll
            for (int i = 0; i < 8; ++i) {
                float s = cq - 2.0f * acc[i][j];
                if (s < best[i]) { best[i] = s; bidx[i] = kg; }
            }
        }
    }
    __syncthreads();
    float* rbest = &xs[0][0];
    int*   ridx  = (int*)&cs[0][0];
    #pragma unroll
    for (int i = 0; i < 8; ++i) {
        rbest[kq * 128 + t0 + i] = best[i];
        ridx [kq * 128 + t0 + i] = bidx[i];
    }
    __syncthreads();
    if (tid < 128) {
        float bv = rbest[tid]; int bi = ridx[tid];
        #pragma unroll
        for (int g = 1; g < 16; ++g) {
            float v = rbest[g * 128 + tid]; int ii = ridx[g * 128 + tid];
            if (v < bv || (v == bv && ii < bi)) { bv = v; bi = ii; }
        }
        idx_f_out[(size_t)b * TT + t_blk + tid] = (float)bi;
    }
}

extern "C" void kernel_launch(void* const* d_in, const int* in_sizes, int n_in,
                              void* d_out, int out_size, void* d_ws, size_t ws_size,
                              hipStream_t stream) {
    const float* x  = (const float*)d_in[0];
    const float* cb = (const float*)d_in[1];
    float* out   = (float*)d_out;
    float* idx_f = out + (size_t)BB * DD * TT;

    if (ws_size >= WS_NEED) {
        h16* xth = (h16*)((char*)d_ws + XTH_OFF);
        h16* xtl = (h16*)((char*)d_ws + XTL_OFF);
        h16* cbh = (h16*)((char*)d_ws + CBH_OFF);
        h16* cbl = (h16*)((char*)d_ws + CBL_OFF);
        float* csq = (float*)((char*)d_ws + CSQ_OFF);

        csq_kernel<<<KK / 4, 256, 0, stream>>>(cb, csq);
        split_cb_kernel<<<128, 256, 0, stream>>>(cb, cbh, cbl);
        split_x_kernel<<<dim3(TT / 128, DD / 32, BB), 256, 0, stream>>>(x, xth, xtl);
        mfma_argmin_kernel<<<dim3(TT / 128, BB), 512, 0, stream>>>(
            xth, xtl, cbh, cbl, csq, cb, idx_f, out);
    } else {
        float* csq = (float*)d_ws;
        csq_kernel<<<KK / 4, 256, 0, stream>>>(cb, csq);
        argmin_fp32_kernel<<<dim3(TT / 128, BB), 256, 0, stream>>>(x, cb, csq, idx_f);
        gather_kernel<<<dim3(TT / 256, BB, 4), 256, 0, stream>>>(cb, idx_f, out);
    }
}

// Round 4
// 484.210 us; speedup vs baseline: 1.1986x; 1.1986x over previous
//
#include <hip/hip_runtime.h>

#define BB 16
#define DD 512
#define TT 4096
#define KK 1024

typedef _Float16 h16;
typedef __attribute__((ext_vector_type(8))) _Float16 half8;
typedef __attribute__((ext_vector_type(4))) float float4v;

// ---- ws layout (main path), bytes ----
// xth/xtl tiled: [b][tb(32)][dcb(16)][128][32] halfs -> 64 MiB per plane
// cbh/cbl tiled: [kb(8)][dcb(16)][128][32] halfs    -> 1 MiB per plane
#define XTH_OFF 0ull
#define XTL_OFF 67108864ull
#define CBH_OFF 134217728ull
#define CBL_OFF 135266304ull
#define CSQ_OFF 136314880ull
#define WS_NEED (136314880ull + 4096ull)

#define GLOAD_LDS16(g, l) __builtin_amdgcn_global_load_lds( \
    (const __attribute__((address_space(1))) void*)(g),      \
    (__attribute__((address_space(3))) void*)(l), 16, 0, 0)

// ---------------------------------------------------------------------------
// csq[k] = sum_d cb[k][d]^2
// ---------------------------------------------------------------------------
__global__ void csq_kernel(const float* __restrict__ cb, float* __restrict__ csq) {
    int wave = threadIdx.x >> 6;
    int lane = threadIdx.x & 63;
    int row  = blockIdx.x * 4 + wave;
    const float* r = cb + (size_t)row * DD;
    float s = 0.f;
    #pragma unroll
    for (int i = 0; i < DD / 64; ++i) { float v = r[lane + i * 64]; s += v * v; }
    #pragma unroll
    for (int off = 32; off; off >>= 1) s += __shfl_down(s, off, 64);
    if (lane == 0) csq[row] = s;
}

// ---------------------------------------------------------------------------
// split x [B][D][T] fp32 -> tiled f16 planes [b][tb][dcb][128][32].
// ---------------------------------------------------------------------------
__global__ __launch_bounds__(256) void split_x_kernel(const float* __restrict__ x,
                                                      h16* __restrict__ xth,
                                                      h16* __restrict__ xtl) {
    __shared__ float xs[32][132];  // float4-stored rows, 16B-aligned stride
    const int tb = blockIdx.x, dcb = blockIdx.y, b = blockIdx.z;
    const int tid = threadIdx.x;
    const int t0 = tb * 128, d0 = dcb * 32;
    const float* xp = x + ((size_t)b * DD + d0) * TT + t0;
    #pragma unroll
    for (int j = 0; j < 4; ++j) {
        int i4 = tid + 256 * j;
        int dd = i4 >> 5, c4 = (i4 & 31) << 2;
        *(float4*)&xs[dd][c4] = *(const float4*)(xp + (size_t)dd * TT + c4);
    }
    __syncthreads();
    const int r = tid >> 1;              // t-local row of output
    const int ch = (tid & 1) * 16;       // d-half
    h16 hv[16], lv[16];
    #pragma unroll
    for (int i = 0; i < 16; ++i) {
        float v = xs[ch + i][r];
        h16 h = (h16)v;
        hv[i] = h;
        lv[i] = (h16)(v - (float)h);
    }
    size_t o = (((size_t)(b * 32 + tb) * 16) + dcb) * 4096 + (size_t)tid * 16;
    *(half8*)(xth + o)     = *(half8*)&hv[0];
    *(half8*)(xth + o + 8) = *(half8*)&hv[8];
    *(half8*)(xtl + o)     = *(half8*)&lv[0];
    *(half8*)(xtl + o + 8) = *(half8*)&lv[8];
}

// ---------------------------------------------------------------------------
// split cb [K][D] fp32 -> tiled f16 planes [kb][dcb][128][32]. No transpose.
// ---------------------------------------------------------------------------
__global__ __launch_bounds__(256) void split_cb_kernel(const float* __restrict__ cb,
                                                       h16* __restrict__ cbh,
                                                       h16* __restrict__ cbl) {
    const int kb = blockIdx.x >> 4, dcb = blockIdx.x & 15;
    const int tid = threadIdx.x;
    const float* cp = cb + ((size_t)kb * 128) * DD + dcb * 32;
    h16* oh = cbh + ((size_t)(kb * 16 + dcb)) * 4096;
    h16* ol = cbl + ((size_t)(kb * 16 + dcb)) * 4096;
    #pragma unroll
    for (int j = 0; j < 4; ++j) {
        int i4 = tid + 256 * j;
        int rr = i4 >> 3, c4 = (i4 & 7) << 2;
        float4 v = *(const float4*)(cp + (size_t)rr * DD + c4);
        float vv[4] = {v.x, v.y, v.z, v.w};
        h16 h[4], l[4];
        #pragma unroll
        for (int i = 0; i < 4; ++i) {
            h[i] = (h16)vv[i];
            l[i] = (h16)(vv[i] - (float)h[i]);
        }
        *(ushort4*)(oh + rr * 32 + c4) = *(ushort4*)h;
        *(ushort4*)(ol + rr * 32 + c4) = *(ushort4*)l;
    }
}

// ---------------------------------------------------------------------------
// fused f16x3-split MFMA GEMM + argmin + gather.
// score[t][k] = csq[k] - 2 * (xh.bh + xh.bl + xl.bh)
// v5: SUPPLY-VOLUME reduction. Evidence (v1/v3/v4): dur tracks total bytes
// moved (~8.2 TB/s fabric), not schedule/LDS/occupancy. The reducible term
// is A-tile re-fetch (once per k-chunk). Widen k-chunk 128 -> 256:
//   kci 8 -> 4, A demand 1 GiB -> 0.5 GiB. Block = 128t x 256k, 8 waves
//   2(wm) x 4(wn), wave tile 64x64, acc[4][4] (v1's proven shape).
// LDS 100 KiB -> 1 block/CU; v3's counted-vmcnt skeleton retained (loads
// in flight across one full MFMA cluster; vmcnt never drains mid-loop).
// Per-acc MFMA order AhBh -> AhBl -> AlBh per dcb, dcb/k ascending:
// bit-identical to previous versions.
// ---------------------------------------------------------------------------
__global__ __launch_bounds__(512, 2) void mfma_argmin_kernel(
    const h16* __restrict__ xth, const h16* __restrict__ xtl,
    const h16* __restrict__ cbh, const h16* __restrict__ cbl,
    const float* __restrict__ csq, const float* __restrict__ cb,
    float* __restrict__ idx_f_out, float* __restrict__ out) {

    __shared__ h16 ash[2][4096];    //  A high plane: [128][32]
    __shared__ h16 asl[2][4096];    //  A low  plane
    __shared__ h16 bsh[2][8192];    //  B high plane: [256][32]
    __shared__ h16 bsl[2][8192];    //  B low  plane
    __shared__ float redv[4][128];
    __shared__ int   redi[4][128];

    const int tid = threadIdx.x;
    const int wid = tid >> 6, lane = tid & 63;
    const int wm = wid & 1;            // t-half of tile (0/1)
    const int wn = wid >> 1;           // k-quarter of 256-chunk (0..3)
    const int tb = blockIdx.x, b = blockIdx.y;
    const int t0 = tb * 128;
    const int c  = lane & 15;          // frag col
    const int q  = lane >> 4;          // frag quad

    const h16* aH = xth + ((size_t)(b * 32 + tb) * 16) * 4096;
    const h16* aL = xtl + ((size_t)(b * 32 + tb) * 16) * 4096;

    const int soff = tid * 8;          // halfs: 512 lanes x 16B = 8 KiB

    // stage tile gi (kci = gi>>4, dcb = gi&15) into buf bf: 6 gloads
    //   A plane (8 KiB each): dcb segment
    //   B plane (16 KiB each): kb = 2*kci and 2*kci+1 segments at dcb
#define STAGE(GI, BF) do {                                                   \
        const int dn_ = (GI) & 15, kc_ = (GI) >> 4;                          \
        const size_t b0_ = ((size_t)(kc_ * 32 + dn_)) * 4096;                \
        const size_t b1_ = ((size_t)(kc_ * 32 + 16 + dn_)) * 4096;          \
        GLOAD_LDS16(aH + (size_t)dn_ * 4096 + soff, &ash[BF][soff]);         \
        GLOAD_LDS16(aL + (size_t)dn_ * 4096 + soff, &asl[BF][soff]);         \
        GLOAD_LDS16(cbh + b0_ + soff, &bsh[BF][soff]);                       \
        GLOAD_LDS16(cbh + b1_ + soff, &bsh[BF][4096 + soff]);                \
        GLOAD_LDS16(cbl + b0_ + soff, &bsl[BF][soff]);                       \
        GLOAD_LDS16(cbl + b1_ + soff, &bsl[BF][4096 + soff]);                \
    } while (0)

    // prologue: stage tiles 0 and 1
    STAGE(0, 0);
    STAGE(1, 1);

    float best[16];
    int   bidx[16];
    #pragma unroll
    for (int i = 0; i < 16; ++i) { best[i] = 3.4e38f; bidx[i] = 0; }

    float4v acc[4][4];
    #pragma unroll
    for (int m = 0; m < 4; ++m)
        #pragma unroll
        for (int n = 0; n < 4; ++n)
            acc[m][n] = (float4v){0.f, 0.f, 0.f, 0.f};

    const int doff = q * 8;

    for (int gi = 0; gi < 64; ++gi) {
        const int bf = gi & 1;

        // current tile's 6 loads done; next tile's 6 stay in flight
        if (gi < 63) asm volatile("s_waitcnt vmcnt(6)" ::: "memory");
        else         asm volatile("s_waitcnt vmcnt(0)" ::: "memory");
        __builtin_amdgcn_s_barrier();

        // ds_read all fragments of the current buffer
        half8 Ah[4], Al[4], Bh[4], Bl[4];
        #pragma unroll
        for (int m = 0; m < 4; ++m) {
            int row = wm * 64 + m * 16 + c;
            Ah[m] = *(const half8*)(&ash[bf][row * 32 + doff]);
            Al[m] = *(const half8*)(&asl[bf][row * 32 + doff]);
        }
        #pragma unroll
        for (int n = 0; n < 4; ++n) {
            int row = wn * 64 + n * 16 + c;   // within 256-row B tile
            Bh[n] = *(const half8*)(&bsh[bf][row * 32 + doff]);
            Bl[n] = *(const half8*)(&bsl[bf][row * 32 + doff]);
        }

        // own reads in regs + all waves past their reads -> buf free
        asm volatile("s_waitcnt lgkmcnt(0)" ::: "memory");
        __builtin_amdgcn_s_barrier();

        if (gi + 2 < 64) STAGE(gi + 2, bf);

        // 48 MFMAs; per-acc chain order AhBh -> AhBl -> AlBh (unchanged)
        #pragma unroll
        for (int n = 0; n < 4; ++n)
            #pragma unroll
            for (int m = 0; m < 4; ++m)
                acc[m][n] = __builtin_amdgcn_mfma_f32_16x16x32_f16(Ah[m], Bh[n], acc[m][n], 0, 0, 0);
        #pragma unroll
        for (int n = 0; n < 4; ++n)
            #pragma unroll
            for (int m = 0; m < 4; ++m)
                acc[m][n] = __builtin_amdgcn_mfma_f32_16x16x32_f16(Ah[m], Bl[n], acc[m][n], 0, 0, 0);
        #pragma unroll
        for (int n = 0; n < 4; ++n)
            #pragma unroll
            for (int m = 0; m < 4; ++m)
                acc[m][n] = __builtin_amdgcn_mfma_f32_16x16x32_f16(Al[m], Bh[n], acc[m][n], 0, 0, 0);

        if ((gi & 15) == 15) {
            // end of 256-wide k-chunk: fold into running argmin
            const int kci = gi >> 4;
            #pragma unroll
            for (int n = 0; n < 4; ++n) {
                int kg = kci * 256 + wn * 64 + n * 16 + c;
                float cq = csq[kg];
                #pragma unroll
                for (int m = 0; m < 4; ++m)
                    #pragma unroll
                    for (int r = 0; r < 4; ++r) {
                        float s = fmaf(-2.0f, acc[m][n][r], cq);
                        int slot = m * 4 + r;
                        if (s < best[slot]) { best[slot] = s; bidx[slot] = kg; }
                    }
            }
            #pragma unroll
            for (int m = 0; m < 4; ++m)
                #pragma unroll
                for (int n = 0; n < 4; ++n)
                    acc[m][n] = (float4v){0.f, 0.f, 0.f, 0.f};
        }
    }
#undef STAGE

    // reduce over the 16 frag columns (lanes sharing a t)
    #pragma unroll
    for (int slot = 0; slot < 16; ++slot) {
        float v = best[slot]; int i = bidx[slot];
        #pragma unroll
        for (int d = 1; d < 16; d <<= 1) {
            float pv = __shfl_xor(v, d);
            int   pi = __shfl_xor(i, d);
            if (pv < v || (pv == v && pi < i)) { v = pv; i = pi; }
        }
        if (c == 0) {
            int m = slot >> 2, r = slot & 3;
            int tl = wm * 64 + m * 16 + q * 4 + r;
            redv[wn][tl] = v; redi[wn][tl] = i;
        }
    }
    __syncthreads();
    if (tid < 128) {
        float v0 = redv[0][tid]; int i0 = redi[0][tid];
        #pragma unroll
        for (int gi = 1; gi < 4; ++gi) {
            float v1 = redv[gi][tid]; int i1 = redi[gi][tid];
            if (v1 < v0 || (v1 == v0 && i1 < i0)) { v0 = v1; i0 = i1; }
        }
        idx_f_out[(size_t)b * TT + t0 + tid] = (float)i0;
        redi[0][tid] = i0;                 // broadcast final index
    }
    __syncthreads();

    // fused gather: out[b][d][t0+tl] = cb[k][d]; 512 threads -> 128 d each
    const int tl = tid & 127, dg = tid >> 7;
    const int k = redi[0][tl];
    const float* row = cb + (size_t)k * DD + dg * 128;
    float* ob = out + ((size_t)b * DD + dg * 128) * TT + t0 + tl;
    #pragma unroll 4
    for (int i = 0; i < 32; ++i) {
        float4 v = *(const float4*)(row + i * 4);
        ob[(size_t)(i * 4 + 0) * TT] = v.x;
        ob[(size_t)(i * 4 + 1) * TT] = v.y;
        ob[(size_t)(i * 4 + 2) * TT] = v.z;
        ob[(size_t)(i * 4 + 3) * TT] = v.w;
    }
}

// ---------------------------------------------------------------------------
// fallback fp32 path + standalone gather (used only if ws too small)
// ---------------------------------------------------------------------------
__global__ void gather_kernel(const float* __restrict__ cb,
                              const float* __restrict__ idx_f,
                              float* __restrict__ out) {
    int b  = blockIdx.y;
    int t  = blockIdx.x * 256 + threadIdx.x;
    int d0 = blockIdx.z * (DD / 4);
    int k  = (int)idx_f[(size_t)b * TT + t];
    const float* row = cb + (size_t)k * DD;
    float* ob = out + (size_t)b * DD * TT + t;
    #pragma unroll 8
    for (int d = d0; d < d0 + DD / 4; ++d)
        ob[(size_t)d * TT] = row[d];
}

__global__ __launch_bounds__(256) void argmin_fp32_kernel(
    const float* __restrict__ x, const float* __restrict__ cb,
    const float* __restrict__ csq, float* __restrict__ idx_f_out) {

    __shared__ float xs[32][128];
    __shared__ float cs[32][132];

    const int tid = threadIdx.x;
    const int b = blockIdx.y;
    const int t_blk = blockIdx.x * 128;
    const int tq = tid & 15, kq = tid >> 4;
    const int t0 = tq * 8, k0 = kq * 8;
    const float* xb = x + (size_t)b * DD * TT;

    float best[8]; int bidx[8];
    #pragma unroll
    for (int i = 0; i < 8; ++i) { best[i] = 3.4e38f; bidx[i] = 0; }

    for (int kc = 0; kc < KK; kc += 128) {
        float acc[8][8];
        #pragma unroll
        for (int i = 0; i < 8; ++i)
            #pragma unroll
            for (int j = 0; j < 8; ++j) acc[i][j] = 0.f;
        for (int dc = 0; dc < DD; dc += 32) {
            __syncthreads();
            #pragma unroll
            for (int j = 0; j < 4; ++j) {
                int i4 = tid + 256 * j;
                int dd = i4 >> 5, tp = (i4 & 31) << 2;
                *(float4*)&xs[dd][tp] =
                    *(const float4*)(xb + (size_t)(dc + dd) * TT + t_blk + tp);
            }
            #pragma unroll
            for (int j = 0; j < 4; ++j) {
                int i4 = tid + 256 * j;
                int kk = i4 >> 3, dq = (i4 & 7) << 2;
                float4 v = *(const float4*)(cb + (size_t)(kc + kk) * DD + dc + dq);
                cs[dq + 0][kk] = v.x; cs[dq + 1][kk] = v.y;
                cs[dq + 2][kk] = v.z; cs[dq + 3][kk] = v.w;
            }
            __syncthreads();
            #pragma unroll 8
            for (int dd = 0; dd < 32; ++dd) {
                float a[8], bv[8];
                *(float4*)&a[0]  = *(const float4*)&xs[dd][t0];
                *(float4*)&a[4]  = *(const float4*)&xs[dd][t0 + 4];
                *(float4*)&bv[0] = *(const float4*)&cs[dd][k0];
                *(float4*)&bv[4] = *(const float4*)&cs[dd][k0 + 4];
                #pragma unroll
                for (int i = 0; i < 8; ++i)
                    #pragma unroll
                    for (int j = 0; j < 8; ++j)
                        acc[i][j] = fmaf(a[i], bv[j], acc[i][j]);
            }
        }
        #pragma unroll
        for (int j = 0; j < 8; ++j) {
            int kg = kc + k0 + j;
            float cq = csq[kg];
            #pragma unroll
            for (int i = 0; i < 8; ++i) {
                float s = cq - 2.0f * acc[i][j];
                if (s < best[i]) { best[i] = s; bidx[i] = kg; }
            }
        }
    }
    __syncthreads();
    float* rbest = &xs[0][0];
    int*   ridx  = (int*)&cs[0][0];
    #pragma unroll
    for (int i = 0; i < 8; ++i) {
        rbest[kq * 128 + t0 + i] = best[i];
        ridx [kq * 128 + t0 + i] = bidx[i];
    }
    __syncthreads();
    if (tid < 128) {
        float bv = rbest[tid]; int bi = ridx[tid];
        #pragma unroll
        for (int g = 1; g < 16; ++g) {
            float v = rbest[g * 128 + tid]; int ii = ridx[g * 128 + tid];
            if (v < bv || (v == bv && ii < bi)) { bv = v; bi = ii; }
        }
        idx_f_out[(size_t)b * TT + t_blk + tid] = (float)bi;
    }
}

extern "C" void kernel_launch(void* const* d_in, const int* in_sizes, int n_in,
                              void* d_out, int out_size, void* d_ws, size_t ws_size,
                              hipStream_t stream) {
    const float* x  = (const float*)d_in[0];
    const float* cb = (const float*)d_in[1];
    float* out   = (float*)d_out;
    float* idx_f = out + (size_t)BB * DD * TT;

    if (ws_size >= WS_NEED) {
        h16* xth = (h16*)((char*)d_ws + XTH_OFF);
        h16* xtl = (h16*)((char*)d_ws + XTL_OFF);
        h16* cbh = (h16*)((char*)d_ws + CBH_OFF);
        h16* cbl = (h16*)((char*)d_ws + CBL_OFF);
        float* csq = (float*)((char*)d_ws + CSQ_OFF);

        csq_kernel<<<KK / 4, 256, 0, stream>>>(cb, csq);
        split_cb_kernel<<<128, 256, 0, stream>>>(cb, cbh, cbl);
        split_x_kernel<<<dim3(TT / 128, DD / 32, BB), 256, 0, stream>>>(x, xth, xtl);
        mfma_argmin_kernel<<<dim3(TT / 128, BB), 512, 0, stream>>>(
            xth, xtl, cbh, cbl, csq, cb, idx_f, out);
    } else {
        float* csq = (float*)d_ws;
        csq_kernel<<<KK / 4, 256, 0, stream>>>(cb, csq);
        argmin_fp32_kernel<<<dim3(TT / 128, BB), 256, 0, stream>>>(x, cb, csq, idx_f);
        gather_kernel<<<dim3(TT / 256, BB, 4), 256, 0, stream>>>(cb, idx_f, out);
    }
}